// Round 1
// baseline (409.611 us; speedup 1.0000x reference)
//
#include <hip/hip_runtime.h>

// 2-layer GCN, R13: agg latency-chain reduction.
// R12 counters: agg1 114us, VALUBusy 44%, "hbm" 45%, occ 77%, VGPR=20 ->
// latency-bound with only 4 gathers in flight and a serial
// colv -> dinv[sl] -> shfl -> h-gather chain per 64-edge batch.
// R13: (a) pre-scale h rows by dinv in the GEMM epilogues (h' = dinv*h), so
// aggregation is out = di*(sum h'[src] + h'[self]) + b  -- no per-edge dinv
// gather, no weight shfl, adds instead of fma pairs; (b) 8-deep gather unroll
// (16/iter in agg2) for 2x memory-level parallelism; (c) nontemporal colv
// loads + hr stores to keep the h-row table hot in L2.
// Preprocessing (count1/write1/degree/fill3/scans) unchanged from R12.

#define N_NODES 100000
#define NBLK  512   // partition blocks
#define NBUCK 391   // ceil(100000/256) buckets of 256 dst nodes

typedef __attribute__((ext_vector_type(8))) short short8;
typedef __attribute__((ext_vector_type(4))) float f32x4;

// ---------- bf16 helpers (RN-even) ----------
__device__ __forceinline__ unsigned short f2bf(float f) {
    union { float f; unsigned u; } c; c.f = f;
    unsigned r = (c.u + 0x7fffu + ((c.u >> 16) & 1u)) >> 16;
    return (unsigned short)r;
}
__device__ __forceinline__ float2 bfpair(unsigned u) {
    union { float f; unsigned u; } a, b;
    a.u = u << 16; b.u = u & 0xffff0000u;
    return make_float2(a.f, b.f);
}
__device__ __forceinline__ unsigned packbf(float a, float b) {
    return (unsigned)f2bf(a) | ((unsigned)f2bf(b) << 16);
}

// ---------- edge dtype detection (one wave) ----------
__global__ void detect64_k(const unsigned long long* __restrict__ ei, int* __restrict__ flag) {
    unsigned long long v = ei[threadIdx.x & 63];
    unsigned long long bad = __ballot(v >= (1ULL << 32));
    if (threadIdx.x == 0) *flag = (bad == 0ULL) ? 1 : 0;
}

__device__ __forceinline__ int edge_at(const void* ei, int is64, long long idx) {
    if (is64) return (int)((const long long*)ei)[idx];
    return ((const int*)ei)[idx];
}

// ---------- pass 1: per-block 391-bucket LDS histogram (NO global atomics) ----------
__global__ __launch_bounds__(256) void count1_k(const void* __restrict__ ei,
                                                const int* __restrict__ flag,
                                                int* __restrict__ bhist, int E) {
    __shared__ int lh[NBUCK];
    int t = threadIdx.x;
    for (int i = t; i < NBUCK; i += 256) lh[i] = 0;
    __syncthreads();
    int is64 = *flag;
    int C = (E + NBLK - 1) / NBLK;
    int lo = blockIdx.x * C;
    int hi = lo + C; if (hi > E) hi = E;
    for (int e = lo + t; e < hi; e += 256) {
        int d = edge_at(ei, is64, (long long)E + e);
        if ((unsigned)d < (unsigned)N_NODES) atomicAdd(&lh[d >> 8], 1);
    }
    __syncthreads();
    for (int i = t; i < NBUCK; i += 256) bhist[(size_t)i * NBLK + blockIdx.x] = lh[i];
}

// ---------- generic exclusive scan, 1024 elems/block ----------
__global__ void scan1_k(const int* __restrict__ cnt, int* __restrict__ partial,
                        int* __restrict__ bsum, int n) {
    __shared__ int sm[256];
    int t = threadIdx.x;
    int base = blockIdx.x * 1024 + t * 4;
    int v[4]; int loc = 0;
#pragma unroll
    for (int j = 0; j < 4; ++j) { v[j] = (base + j < n) ? cnt[base + j] : 0; loc += v[j]; }
    sm[t] = loc; __syncthreads();
    for (int off = 1; off < 256; off <<= 1) {
        int x = (t >= off) ? sm[t - off] : 0;
        __syncthreads();
        sm[t] += x;
        __syncthreads();
    }
    int incl = sm[t];
    int run = incl - loc;
    if (t == 255) bsum[blockIdx.x] = incl;
#pragma unroll
    for (int j = 0; j < 4; ++j) {
        if (base + j < n) partial[base + j] = run;
        run += v[j];
    }
}

__global__ void scan2_k(int* __restrict__ bsum, int nb) {
    __shared__ int sm[256];
    int t = threadIdx.x;
    int v = (t < nb) ? bsum[t] : 0;
    sm[t] = v; __syncthreads();
    for (int off = 1; off < 256; off <<= 1) {
        int x = (t >= off) ? sm[t - off] : 0;
        __syncthreads();
        sm[t] += x;
        __syncthreads();
    }
    if (t < nb) bsum[t] = sm[t] - v;
}

// finalize bucket-base scan in place; also emit total valid count
__global__ void scanadd_k(const int* __restrict__ bsum, int* __restrict__ arr,
                          const int* __restrict__ raw, int* __restrict__ tot, int n) {
    int base = blockIdx.x * 1024 + threadIdx.x * 4;
    int add = bsum[blockIdx.x];
#pragma unroll
    for (int j = 0; j < 4; ++j) {
        int i = base + j;
        if (i < n) {
            int v = arr[i] + add;
            arr[i] = v;
            if (i == n - 1) *tot = v + raw[i];
        }
    }
}

// finalize degree scan: row_ptr + dinv
__global__ void scan3_k(const int* __restrict__ bsum, const int* __restrict__ cnt,
                        int* __restrict__ row_ptr, float* __restrict__ dinv, int n) {
    int base = blockIdx.x * 1024 + threadIdx.x * 4;
    int add = bsum[blockIdx.x];
#pragma unroll
    for (int j = 0; j < 4; ++j) {
        int i = base + j;
        if (i < n) {
            row_ptr[i] += add;
            dinv[i] = rsqrtf((float)(cnt[i] + 1));  // +1 self-loop
        }
    }
}

// ---------- pass 2: deterministic staging write (src | dlocal<<17) ----------
__global__ __launch_bounds__(256) void write1_k(const void* __restrict__ ei,
                                                const int* __restrict__ flag,
                                                const int* __restrict__ bbase,
                                                unsigned* __restrict__ pairs, int E) {
    __shared__ int lofs[NBUCK];
    int t = threadIdx.x;
    for (int i = t; i < NBUCK; i += 256) lofs[i] = bbase[(size_t)i * NBLK + blockIdx.x];
    __syncthreads();
    int is64 = *flag;
    int C = (E + NBLK - 1) / NBLK;
    int lo = blockIdx.x * C;
    int hi = lo + C; if (hi > E) hi = E;
    for (int e = lo + t; e < hi; e += 256) {
        int s = edge_at(ei, is64, e);
        int d = edge_at(ei, is64, (long long)E + e);
        if ((unsigned)d >= (unsigned)N_NODES) continue;         // must match count1 filter
        if ((unsigned)s >= (unsigned)N_NODES) s = 0;            // clamp keeps counts consistent
        int b = d >> 8;
        int p = atomicAdd(&lofs[b], 1);  // LDS atomic; per-block fronts contiguous
        pairs[p] = (unsigned)s | ((unsigned)(d & 255) << 17);
    }
}

// ---------- degrees from staged pairs: one block per bucket, block-private writes ----------
__global__ __launch_bounds__(256) void degree_k(const unsigned* __restrict__ pairs,
                                                const int* __restrict__ bbase,
                                                const int* __restrict__ tot,
                                                int* __restrict__ cnt, int Nn) {
    __shared__ int lh[256];
    int b = blockIdx.x;
    int t = threadIdx.x;
    lh[t] = 0;
    __syncthreads();
    int lo = bbase[(size_t)b * NBLK];
    int hi = (b == NBUCK - 1) ? *tot : bbase[((size_t)b + 1) * NBLK];
    for (int i = lo + t; i < hi; i += 256) {
        unsigned p = __builtin_nontemporal_load(pairs + i);
        atomicAdd(&lh[p >> 17], 1);
    }
    __syncthreads();
    int n0 = b << 8;
    if (n0 + t < Nn) cnt[n0 + t] = lh[t];
}

// ---------- pass 3: block-private scatter into exact CSR positions ----------
__global__ __launch_bounds__(256) void fill3_k(const unsigned* __restrict__ pairs,
                                               const int* __restrict__ bbase,
                                               const int* __restrict__ tot,
                                               const int* __restrict__ row_ptr,
                                               int* __restrict__ colv, int Nn) {
    __shared__ int cur[256];
    int b = blockIdx.x;
    int t = threadIdx.x;
    int n0 = b << 8;
    int nn = Nn - n0; if (nn > 256) nn = 256;
    if (t < nn) cur[t] = row_ptr[n0 + t];
    __syncthreads();
    int lo = bbase[(size_t)b * NBLK];
    int hi = (b == NBUCK - 1) ? *tot : bbase[((size_t)b + 1) * NBLK];
    for (int i = lo + t; i < hi; i += 256) {
        unsigned p = __builtin_nontemporal_load(pairs + i);
        int dl = (int)(p >> 17);
        int slot = atomicAdd(&cur[dl], 1);
        colv[slot] = (int)(p & 0x1FFFFu);   // block-private ~32KB range: no line sharing
    }
}

// ---------- weight prep: W^T in bf16 ----------
__global__ void prep_w_k(const float* __restrict__ W1, const float* __restrict__ W2,
                         unsigned short* __restrict__ w1bf, unsigned short* __restrict__ w2bf) {
    int i = blockIdx.x * 256 + threadIdx.x;
    if (i < 128 * 128) { int k = i >> 7, f = i & 127; w1bf[f * 128 + k] = f2bf(W1[i]); }
    if (i < 128 * 64)  { int k = i >> 6, f = i & 63;  w2bf[f * 128 + k] = f2bf(W2[i]); }
}

// ---------- GEMM1 (MFMA): h1[n][128] bf16 node-major = dinv[n] * (x @ W1) ----------
__global__ __launch_bounds__(256) void gemm1_k(const float* __restrict__ x,
                                               const unsigned short* __restrict__ w1bf,
                                               const float* __restrict__ dinv,
                                               unsigned* __restrict__ h1, int Nn) {
    __shared__ __align__(16) unsigned short sA[128][136];  // W1^T [feat][k]
    __shared__ __align__(16) unsigned short sB[64][136];   // x [node][k] bf16
    int tid = threadIdx.x;
    int n0g = blockIdx.x * 64;
    {
        const uint4* src = (const uint4*)w1bf;
#pragma unroll
        for (int l = 0; l < 8; ++l) {
            int idx = tid + l * 256;
            int f = idx >> 4, kq = idx & 15;
            *(uint4*)&sA[f][kq * 8] = src[idx];
        }
    }
    {
        int n = tid >> 2, kq = tid & 3;
        int gn = n0g + n; if (gn >= Nn) gn = Nn - 1;
        const float4* xr = (const float4*)(x + (size_t)gn * 128 + kq * 32);
        unsigned short* dst = &sB[n][kq * 32];
#pragma unroll
        for (int i = 0; i < 8; ++i) {
            float4 v = xr[i];
            dst[i * 4 + 0] = f2bf(v.x); dst[i * 4 + 1] = f2bf(v.y);
            dst[i * 4 + 2] = f2bf(v.z); dst[i * 4 + 3] = f2bf(v.w);
        }
    }
    __syncthreads();
    int wave = tid >> 6, lane = tid & 63;
    int quad = lane >> 4, l16 = lane & 15;
    f32x4 z = {0.f, 0.f, 0.f, 0.f};
    f32x4 acc[8];
#pragma unroll
    for (int t = 0; t < 8; ++t) acc[t] = z;
#pragma unroll
    for (int kk = 0; kk < 4; ++kk) {
        int kb = kk * 32 + quad * 8;
        short8 a = *(const short8*)&sB[wave * 16 + l16][kb];
#pragma unroll
        for (int ft = 0; ft < 8; ++ft) {
            short8 b = *(const short8*)&sA[ft * 16 + l16][kb];
            acc[ft] = __builtin_amdgcn_mfma_f32_16x16x32_bf16(a, b, acc[ft], 0, 0, 0);
        }
    }
    // per-row dinv for pre-scaled h' = dinv * h
    float dv[4];
#pragma unroll
    for (int r = 0; r < 4; ++r) {
        int gn = n0g + wave * 16 + quad * 4 + r;
        if (gn >= Nn) gn = Nn - 1;
        dv[r] = dinv[gn];
    }
    __syncthreads();  // reuse sA as transpose buffer
    unsigned short (*sC)[136] = sA;
#pragma unroll
    for (int ft = 0; ft < 8; ++ft)
#pragma unroll
        for (int r = 0; r < 4; ++r)
            sC[wave * 16 + quad * 4 + r][ft * 16 + l16] = f2bf(dv[r] * acc[ft][r]);
    __syncthreads();
#pragma unroll
    for (int l = 0; l < 4; ++l) {
        int idx = tid + l * 256;
        int row = idx >> 4, q = idx & 15;
        int gn = n0g + row;
        if (gn < Nn)
            *(uint4*)&h1[(size_t)gn * 64 + q * 4] = *(uint4*)&sC[row][q * 8];
    }
}

// ---------- GEMM2 (MFMA): h2[n][64] bf16 node-major = dinv[n] * (hr @ W2) ----------
__global__ __launch_bounds__(256) void gemm2_k(const unsigned* __restrict__ hr,
                                               const unsigned short* __restrict__ w2bf,
                                               const float* __restrict__ dinv,
                                               unsigned* __restrict__ h2, int Nn) {
    __shared__ __align__(16) unsigned short sA[64][136];
    __shared__ __align__(16) unsigned short sB[64][136];
    int tid = threadIdx.x;
    int n0g = blockIdx.x * 64;
    {
        const uint4* src = (const uint4*)w2bf;
#pragma unroll
        for (int l = 0; l < 4; ++l) {
            int idx = tid + l * 256;
            int f = idx >> 4, kq = idx & 15;
            *(uint4*)&sA[f][kq * 8] = src[idx];
        }
    }
    {
        const uint4* src = (const uint4*)hr;
#pragma unroll
        for (int l = 0; l < 4; ++l) {
            int idx = tid + l * 256;
            int row = idx >> 4, q = idx & 15;
            int gn = n0g + row; if (gn >= Nn) gn = Nn - 1;
            *(uint4*)&sB[row][q * 8] = src[(size_t)gn * 16 + q];
        }
    }
    __syncthreads();
    int wave = tid >> 6, lane = tid & 63;
    int quad = lane >> 4, l16 = lane & 15;
    f32x4 z = {0.f, 0.f, 0.f, 0.f};
    f32x4 acc[4];
#pragma unroll
    for (int t = 0; t < 4; ++t) acc[t] = z;
#pragma unroll
    for (int kk = 0; kk < 4; ++kk) {
        int kb = kk * 32 + quad * 8;
        short8 a = *(const short8*)&sB[wave * 16 + l16][kb];
#pragma unroll
        for (int ft = 0; ft < 4; ++ft) {
            short8 b = *(const short8*)&sA[ft * 16 + l16][kb];
            acc[ft] = __builtin_amdgcn_mfma_f32_16x16x32_bf16(a, b, acc[ft], 0, 0, 0);
        }
    }
    float dv[4];
#pragma unroll
    for (int r = 0; r < 4; ++r) {
        int gn = n0g + wave * 16 + quad * 4 + r;
        if (gn >= Nn) gn = Nn - 1;
        dv[r] = dinv[gn];
    }
    __syncthreads();
    unsigned short (*sC)[136] = sA;
#pragma unroll
    for (int ft = 0; ft < 4; ++ft)
#pragma unroll
        for (int r = 0; r < 4; ++r)
            sC[wave * 16 + quad * 4 + r][ft * 16 + l16] = f2bf(dv[r] * acc[ft][r]);
    __syncthreads();
#pragma unroll
    for (int l = 0; l < 2; ++l) {
        int idx = tid + l * 256;
        int row = idx >> 3, q = idx & 7;
        int gn = n0g + row;
        if (gn < Nn)
            *(uint4*)&h2[(size_t)gn * 32 + q * 4] = *(uint4*)&sC[row][q * 8];
    }
}

// ---------- agg1: wave=node, h pre-scaled by dinv[src]; 8-deep gather MLP ----------
// out[dst] = relu( di * (sum_src h'[src] + h'[dst]) + b )
__global__ __launch_bounds__(256) void agg1_k(const unsigned* __restrict__ h,
                                              const int* __restrict__ row_ptr,
                                              const int* __restrict__ cnt,
                                              const int* __restrict__ colv,
                                              const float* __restrict__ dinv,
                                              const float* __restrict__ bias,
                                              unsigned* __restrict__ out, int Nn, int E) {
    int node = blockIdx.x * 4 + (threadIdx.x >> 6);
    if (node >= Nn) return;
    int lane = threadIdx.x & 63;
    float di = dinv[node];
    int start = row_ptr[node];
    int deg = cnt[node];

    float2 hv = bfpair(h[(size_t)node * 64 + lane]);  // self (already * di)
    float ax = hv.x, ay = hv.y;

    for (int base = 0; base < deg; base += 64) {
        int idx = base + lane;
        int ci = start + idx; if (ci >= E) ci = E - 1;
        int sl = __builtin_nontemporal_load(colv + ci);
        int m = deg - base; if (m > 64) m = 64;
        int j = 0;
        for (; j + 8 <= m; j += 8) {
            int s0 = __shfl(sl, j),     s1 = __shfl(sl, j + 1);
            int s2 = __shfl(sl, j + 2), s3 = __shfl(sl, j + 3);
            int s4 = __shfl(sl, j + 4), s5 = __shfl(sl, j + 5);
            int s6 = __shfl(sl, j + 6), s7 = __shfl(sl, j + 7);
            unsigned u0 = h[(size_t)s0 * 64 + lane];
            unsigned u1 = h[(size_t)s1 * 64 + lane];
            unsigned u2 = h[(size_t)s2 * 64 + lane];
            unsigned u3 = h[(size_t)s3 * 64 + lane];
            unsigned u4 = h[(size_t)s4 * 64 + lane];
            unsigned u5 = h[(size_t)s5 * 64 + lane];
            unsigned u6 = h[(size_t)s6 * 64 + lane];
            unsigned u7 = h[(size_t)s7 * 64 + lane];
            float2 v0 = bfpair(u0), v1 = bfpair(u1), v2 = bfpair(u2), v3 = bfpair(u3);
            float2 v4 = bfpair(u4), v5 = bfpair(u5), v6 = bfpair(u6), v7 = bfpair(u7);
            ax += ((v0.x + v1.x) + (v2.x + v3.x)) + ((v4.x + v5.x) + (v6.x + v7.x));
            ay += ((v0.y + v1.y) + (v2.y + v3.y)) + ((v4.y + v5.y) + (v6.y + v7.y));
        }
        for (; j + 4 <= m; j += 4) {
            int s0 = __shfl(sl, j),     s1 = __shfl(sl, j + 1);
            int s2 = __shfl(sl, j + 2), s3 = __shfl(sl, j + 3);
            unsigned u0 = h[(size_t)s0 * 64 + lane];
            unsigned u1 = h[(size_t)s1 * 64 + lane];
            unsigned u2 = h[(size_t)s2 * 64 + lane];
            unsigned u3 = h[(size_t)s3 * 64 + lane];
            float2 v0 = bfpair(u0), v1 = bfpair(u1), v2 = bfpair(u2), v3 = bfpair(u3);
            ax += (v0.x + v1.x) + (v2.x + v3.x);
            ay += (v0.y + v1.y) + (v2.y + v3.y);
        }
        for (; j < m; ++j) {
            int s = __shfl(sl, j);
            float2 v = bfpair(h[(size_t)s * 64 + lane]);
            ax += v.x; ay += v.y;
        }
    }
    float r0 = fmaxf(fmaf(di, ax, bias[lane * 2]), 0.f);
    float r1 = fmaxf(fmaf(di, ay, bias[lane * 2 + 1]), 0.f);
    __builtin_nontemporal_store(packbf(r0, r1), &out[(size_t)node * 64 + lane]);
}

// ---------- agg2: wave=node, 2 edges per gather instruction, 16-deep unroll ----------
__global__ __launch_bounds__(256) void agg2_k(const unsigned* __restrict__ h,
                                              const int* __restrict__ row_ptr,
                                              const int* __restrict__ cnt,
                                              const int* __restrict__ colv,
                                              const float* __restrict__ dinv,
                                              const float* __restrict__ bias,
                                              float* __restrict__ out, int Nn, int E) {
    int node = blockIdx.x * 4 + (threadIdx.x >> 6);
    if (node >= Nn) return;
    int lane = threadIdx.x & 63;
    int half = lane >> 5, fp = lane & 31;
    float di = dinv[node];
    int start = row_ptr[node];
    int deg = cnt[node];

    float2 hv = bfpair(h[(size_t)node * 32 + fp]);  // self (already * di)
    float ax = (half == 0) ? hv.x : 0.f;
    float ay = (half == 0) ? hv.y : 0.f;

    for (int base = 0; base < deg; base += 64) {
        int idx = base + lane;
        int ci = start + idx; if (ci >= E) ci = E - 1;
        int sl = __builtin_nontemporal_load(colv + ci);
        int m = deg - base; if (m > 64) m = 64;
        int j = 0;
        for (; j + 16 <= m; j += 16) {
            int q0 = j + half,      q1 = j + 2 + half,  q2 = j + 4 + half,  q3 = j + 6 + half;
            int q4 = j + 8 + half,  q5 = j + 10 + half, q6 = j + 12 + half, q7 = j + 14 + half;
            int s0 = __shfl(sl, q0), s1 = __shfl(sl, q1);
            int s2 = __shfl(sl, q2), s3 = __shfl(sl, q3);
            int s4 = __shfl(sl, q4), s5 = __shfl(sl, q5);
            int s6 = __shfl(sl, q6), s7 = __shfl(sl, q7);
            unsigned u0 = h[(size_t)s0 * 32 + fp];
            unsigned u1 = h[(size_t)s1 * 32 + fp];
            unsigned u2 = h[(size_t)s2 * 32 + fp];
            unsigned u3 = h[(size_t)s3 * 32 + fp];
            unsigned u4 = h[(size_t)s4 * 32 + fp];
            unsigned u5 = h[(size_t)s5 * 32 + fp];
            unsigned u6 = h[(size_t)s6 * 32 + fp];
            unsigned u7 = h[(size_t)s7 * 32 + fp];
            float2 v0 = bfpair(u0), v1 = bfpair(u1), v2 = bfpair(u2), v3 = bfpair(u3);
            float2 v4 = bfpair(u4), v5 = bfpair(u5), v6 = bfpair(u6), v7 = bfpair(u7);
            ax += ((v0.x + v1.x) + (v2.x + v3.x)) + ((v4.x + v5.x) + (v6.x + v7.x));
            ay += ((v0.y + v1.y) + (v2.y + v3.y)) + ((v4.y + v5.y) + (v6.y + v7.y));
        }
        for (; j + 8 <= m; j += 8) {
            int q0 = j + half, q1 = j + 2 + half, q2 = j + 4 + half, q3 = j + 6 + half;
            int s0 = __shfl(sl, q0), s1 = __shfl(sl, q1);
            int s2 = __shfl(sl, q2), s3 = __shfl(sl, q3);
            unsigned u0 = h[(size_t)s0 * 32 + fp];
            unsigned u1 = h[(size_t)s1 * 32 + fp];
            unsigned u2 = h[(size_t)s2 * 32 + fp];
            unsigned u3 = h[(size_t)s3 * 32 + fp];
            float2 v0 = bfpair(u0), v1 = bfpair(u1), v2 = bfpair(u2), v3 = bfpair(u3);
            ax += (v0.x + v1.x) + (v2.x + v3.x);
            ay += (v0.y + v1.y) + (v2.y + v3.y);
        }
        for (; j < m; j += 2) {
            int q = j + half;
            int s = __shfl(sl, q & 63);
            float w = (q < m) ? 1.f : 0.f;
            float2 v = bfpair(h[(size_t)s * 32 + fp]);
            ax = fmaf(w, v.x, ax); ay = fmaf(w, v.y, ay);
        }
    }
    ax += __shfl_xor(ax, 32, 64);
    ay += __shfl_xor(ay, 32, 64);
    if (half == 0) {
        float2 r = make_float2(fmaf(di, ax, bias[fp * 2]), fmaf(di, ay, bias[fp * 2 + 1]));
        *(float2*)&out[(size_t)node * 64 + fp * 2] = r;
    }
}

// ---------- launch ----------
extern "C" void kernel_launch(void* const* d_in, const int* in_sizes, int n_in,
                              void* d_out, int out_size, void* d_ws, size_t ws_size,
                              hipStream_t stream) {
    const float* x  = (const float*)d_in[0];
    const void*  ei = d_in[1];
    const float* W1 = (const float*)d_in[2];
    const float* b1 = (const float*)d_in[3];
    const float* W2 = (const float*)d_in[4];
    const float* b2 = (const float*)d_in[5];

    const int N = N_NODES;
    const int E = in_sizes[1] / 2;
    const int NB = NBLK * NBUCK;  // 200192

    char* w = (char*)d_ws;
    size_t off = 0;
    auto take = [&](size_t bytes) {
        void* p = w + off;
        off = (off + bytes + 255) & ~(size_t)255;
        return p;
    };
    int*   flag    = (int*)take(2 * sizeof(int));
    int*   tot     = flag + 1;
    int*   cnt     = (int*)take((size_t)N * 4);
    int*   row_ptr = (int*)take((size_t)N * 4);
    int*   bsumA   = (int*)take(256 * 4);
    int*   bsumB   = (int*)take(256 * 4);
    int*   bhist   = (int*)take((size_t)NB * 4);
    int*   bbase   = (int*)take((size_t)NB * 4);
    float* dinv    = (float*)take((size_t)N * 4);
    unsigned* pairs = (unsigned*)take((size_t)E * 4);
    int*   colv    = (int*)take((size_t)E * 4);
    unsigned short* w1bf = (unsigned short*)take(128 * 128 * 2);
    unsigned short* w2bf = (unsigned short*)take(64 * 128 * 2);
    unsigned* hr   = (unsigned*)take((size_t)N * 64 * 4);   // bf16 [N][128]
    unsigned* h2   = (unsigned*)take((size_t)N * 32 * 4);   // bf16 [N][64]
    (void)ws_size; (void)n_in; (void)out_size;

    unsigned* h1 = (unsigned*)d_out;  // bf16 [N][128] in d_out, dead before agg2 writes

    const int nscanN = (N + 1023) / 1024;   // 98
    const int nscanB = (NB + 1023) / 1024;  // 196

    detect64_k<<<1, 64, 0, stream>>>((const unsigned long long*)ei, flag);
    count1_k<<<NBLK, 256, 0, stream>>>(ei, flag, bhist, E);
    // bucket-base scan (exclusive over bucket-major [NBUCK][NBLK])
    scan1_k<<<nscanB, 256, 0, stream>>>(bhist, bbase, bsumB, NB);
    scan2_k<<<1, 256, 0, stream>>>(bsumB, nscanB);
    scanadd_k<<<nscanB, 256, 0, stream>>>(bsumB, bbase, bhist, tot, NB);
    // stage pairs, then block-private degrees
    write1_k<<<NBLK, 256, 0, stream>>>(ei, flag, bbase, pairs, E);
    degree_k<<<NBUCK, 256, 0, stream>>>(pairs, bbase, tot, cnt, N);
    // degree scan -> row_ptr, dinv
    scan1_k<<<nscanN, 256, 0, stream>>>(cnt, row_ptr, bsumA, N);
    scan2_k<<<1, 256, 0, stream>>>(bsumA, nscanN);
    scan3_k<<<nscanN, 256, 0, stream>>>(bsumA, cnt, row_ptr, dinv, N);
    // block-private CSR scatter
    fill3_k<<<NBUCK, 256, 0, stream>>>(pairs, bbase, tot, row_ptr, colv, N);
    prep_w_k<<<64, 256, 0, stream>>>(W1, W2, w1bf, w2bf);

    gemm1_k<<<(N + 63) / 64, 256, 0, stream>>>(x, w1bf, dinv, h1, N);
    agg1_k<<<(N + 3) / 4, 256, 0, stream>>>(h1, row_ptr, cnt, colv, dinv, b1, hr, N, E);
    gemm2_k<<<(N + 63) / 64, 256, 0, stream>>>(hr, w2bf, dinv, h2, N);
    agg2_k<<<(N + 3) / 4, 256, 0, stream>>>(h2, row_ptr, cnt, colv, dinv, b2, (float*)d_out, N, E);
}

// Round 2
// 394.683 us; speedup vs baseline: 1.0378x; 1.0378x over previous
//
#include <hip/hip_runtime.h>

// 2-layer GCN, R14: wide-gather aggregation.
// R13 counters: agg1 106.7us, VALUBusy 43%, hbm 46%, VGPR=20 -> co-limited by
// VALU instruction issue (~8 wave-instrs/edge) and gather latency. R14:
// (a) uint4 gathers: 16 lanes cover one 256B h1 row -> 4 edges per load
//     instruction (agg1); 8 lanes per 128B h2 row -> 8 edges/load (agg2).
//     Loads, shfl-broadcasts, and address VALU per edge drop 4-8x.
// (b) f32x2 packed accumulators (v_pk_add_f32) for the unpack-add chain.
// (c) Revert R13's NT store of hr (gemm2 re-reads it; NT evicted it from L2)
//     and NT colv load in agg1 (agg2 may still reuse); NT kept only on
//     agg2's colv (true last use).
// Preprocessing + GEMMs (dinv-prescaled epilogues) unchanged from R13.

#define N_NODES 100000
#define NBLK  512   // partition blocks
#define NBUCK 391   // ceil(100000/256) buckets of 256 dst nodes

typedef __attribute__((ext_vector_type(8))) short short8;
typedef __attribute__((ext_vector_type(4))) float f32x4;
typedef __attribute__((ext_vector_type(2))) float f32x2;

// ---------- bf16 helpers (RN-even) ----------
__device__ __forceinline__ unsigned short f2bf(float f) {
    union { float f; unsigned u; } c; c.f = f;
    unsigned r = (c.u + 0x7fffu + ((c.u >> 16) & 1u)) >> 16;
    return (unsigned short)r;
}
__device__ __forceinline__ float2 bfpair(unsigned u) {
    union { float f; unsigned u; } a, b;
    a.u = u << 16; b.u = u & 0xffff0000u;
    return make_float2(a.f, b.f);
}
__device__ __forceinline__ unsigned packbf(float a, float b) {
    return (unsigned)f2bf(a) | ((unsigned)f2bf(b) << 16);
}
// accumulate one packed-bf16 u32 into a packed f32x2 (lo feature, hi feature)
__device__ __forceinline__ void bfacc(unsigned u, f32x2& a) {
    union { unsigned u; float f; } lo, hi;
    lo.u = u << 16; hi.u = u & 0xffff0000u;
    f32x2 v = {lo.f, hi.f};
    a += v;   // v_pk_add_f32
}
__device__ __forceinline__ void bfacc4(uint4 u, f32x2& a0, f32x2& a1, f32x2& a2, f32x2& a3) {
    bfacc(u.x, a0); bfacc(u.y, a1); bfacc(u.z, a2); bfacc(u.w, a3);
}

// ---------- edge dtype detection (one wave) ----------
__global__ void detect64_k(const unsigned long long* __restrict__ ei, int* __restrict__ flag) {
    unsigned long long v = ei[threadIdx.x & 63];
    unsigned long long bad = __ballot(v >= (1ULL << 32));
    if (threadIdx.x == 0) *flag = (bad == 0ULL) ? 1 : 0;
}

__device__ __forceinline__ int edge_at(const void* ei, int is64, long long idx) {
    if (is64) return (int)((const long long*)ei)[idx];
    return ((const int*)ei)[idx];
}

// ---------- pass 1: per-block 391-bucket LDS histogram (NO global atomics) ----------
__global__ __launch_bounds__(256) void count1_k(const void* __restrict__ ei,
                                                const int* __restrict__ flag,
                                                int* __restrict__ bhist, int E) {
    __shared__ int lh[NBUCK];
    int t = threadIdx.x;
    for (int i = t; i < NBUCK; i += 256) lh[i] = 0;
    __syncthreads();
    int is64 = *flag;
    int C = (E + NBLK - 1) / NBLK;
    int lo = blockIdx.x * C;
    int hi = lo + C; if (hi > E) hi = E;
    for (int e = lo + t; e < hi; e += 256) {
        int d = edge_at(ei, is64, (long long)E + e);
        if ((unsigned)d < (unsigned)N_NODES) atomicAdd(&lh[d >> 8], 1);
    }
    __syncthreads();
    for (int i = t; i < NBUCK; i += 256) bhist[(size_t)i * NBLK + blockIdx.x] = lh[i];
}

// ---------- generic exclusive scan, 1024 elems/block ----------
__global__ void scan1_k(const int* __restrict__ cnt, int* __restrict__ partial,
                        int* __restrict__ bsum, int n) {
    __shared__ int sm[256];
    int t = threadIdx.x;
    int base = blockIdx.x * 1024 + t * 4;
    int v[4]; int loc = 0;
#pragma unroll
    for (int j = 0; j < 4; ++j) { v[j] = (base + j < n) ? cnt[base + j] : 0; loc += v[j]; }
    sm[t] = loc; __syncthreads();
    for (int off = 1; off < 256; off <<= 1) {
        int x = (t >= off) ? sm[t - off] : 0;
        __syncthreads();
        sm[t] += x;
        __syncthreads();
    }
    int incl = sm[t];
    int run = incl - loc;
    if (t == 255) bsum[blockIdx.x] = incl;
#pragma unroll
    for (int j = 0; j < 4; ++j) {
        if (base + j < n) partial[base + j] = run;
        run += v[j];
    }
}

__global__ void scan2_k(int* __restrict__ bsum, int nb) {
    __shared__ int sm[256];
    int t = threadIdx.x;
    int v = (t < nb) ? bsum[t] : 0;
    sm[t] = v; __syncthreads();
    for (int off = 1; off < 256; off <<= 1) {
        int x = (t >= off) ? sm[t - off] : 0;
        __syncthreads();
        sm[t] += x;
        __syncthreads();
    }
    if (t < nb) bsum[t] = sm[t] - v;
}

// finalize bucket-base scan in place; also emit total valid count
__global__ void scanadd_k(const int* __restrict__ bsum, int* __restrict__ arr,
                          const int* __restrict__ raw, int* __restrict__ tot, int n) {
    int base = blockIdx.x * 1024 + threadIdx.x * 4;
    int add = bsum[blockIdx.x];
#pragma unroll
    for (int j = 0; j < 4; ++j) {
        int i = base + j;
        if (i < n) {
            int v = arr[i] + add;
            arr[i] = v;
            if (i == n - 1) *tot = v + raw[i];
        }
    }
}

// finalize degree scan: row_ptr + dinv
__global__ void scan3_k(const int* __restrict__ bsum, const int* __restrict__ cnt,
                        int* __restrict__ row_ptr, float* __restrict__ dinv, int n) {
    int base = blockIdx.x * 1024 + threadIdx.x * 4;
    int add = bsum[blockIdx.x];
#pragma unroll
    for (int j = 0; j < 4; ++j) {
        int i = base + j;
        if (i < n) {
            row_ptr[i] += add;
            dinv[i] = rsqrtf((float)(cnt[i] + 1));  // +1 self-loop
        }
    }
}

// ---------- pass 2: deterministic staging write (src | dlocal<<17) ----------
__global__ __launch_bounds__(256) void write1_k(const void* __restrict__ ei,
                                                const int* __restrict__ flag,
                                                const int* __restrict__ bbase,
                                                unsigned* __restrict__ pairs, int E) {
    __shared__ int lofs[NBUCK];
    int t = threadIdx.x;
    for (int i = t; i < NBUCK; i += 256) lofs[i] = bbase[(size_t)i * NBLK + blockIdx.x];
    __syncthreads();
    int is64 = *flag;
    int C = (E + NBLK - 1) / NBLK;
    int lo = blockIdx.x * C;
    int hi = lo + C; if (hi > E) hi = E;
    for (int e = lo + t; e < hi; e += 256) {
        int s = edge_at(ei, is64, e);
        int d = edge_at(ei, is64, (long long)E + e);
        if ((unsigned)d >= (unsigned)N_NODES) continue;         // must match count1 filter
        if ((unsigned)s >= (unsigned)N_NODES) s = 0;            // clamp keeps counts consistent
        int b = d >> 8;
        int p = atomicAdd(&lofs[b], 1);  // LDS atomic; per-block fronts contiguous
        pairs[p] = (unsigned)s | ((unsigned)(d & 255) << 17);
    }
}

// ---------- degrees from staged pairs: one block per bucket, block-private writes ----------
__global__ __launch_bounds__(256) void degree_k(const unsigned* __restrict__ pairs,
                                                const int* __restrict__ bbase,
                                                const int* __restrict__ tot,
                                                int* __restrict__ cnt, int Nn) {
    __shared__ int lh[256];
    int b = blockIdx.x;
    int t = threadIdx.x;
    lh[t] = 0;
    __syncthreads();
    int lo = bbase[(size_t)b * NBLK];
    int hi = (b == NBUCK - 1) ? *tot : bbase[((size_t)b + 1) * NBLK];
    for (int i = lo + t; i < hi; i += 256) {
        unsigned p = __builtin_nontemporal_load(pairs + i);
        atomicAdd(&lh[p >> 17], 1);
    }
    __syncthreads();
    int n0 = b << 8;
    if (n0 + t < Nn) cnt[n0 + t] = lh[t];
}

// ---------- pass 3: block-private scatter into exact CSR positions ----------
__global__ __launch_bounds__(256) void fill3_k(const unsigned* __restrict__ pairs,
                                               const int* __restrict__ bbase,
                                               const int* __restrict__ tot,
                                               const int* __restrict__ row_ptr,
                                               int* __restrict__ colv, int Nn) {
    __shared__ int cur[256];
    int b = blockIdx.x;
    int t = threadIdx.x;
    int n0 = b << 8;
    int nn = Nn - n0; if (nn > 256) nn = 256;
    if (t < nn) cur[t] = row_ptr[n0 + t];
    __syncthreads();
    int lo = bbase[(size_t)b * NBLK];
    int hi = (b == NBUCK - 1) ? *tot : bbase[((size_t)b + 1) * NBLK];
    for (int i = lo + t; i < hi; i += 256) {
        unsigned p = __builtin_nontemporal_load(pairs + i);
        int dl = (int)(p >> 17);
        int slot = atomicAdd(&cur[dl], 1);
        colv[slot] = (int)(p & 0x1FFFFu);   // block-private ~32KB range: no line sharing
    }
}

// ---------- weight prep: W^T in bf16 ----------
__global__ void prep_w_k(const float* __restrict__ W1, const float* __restrict__ W2,
                         unsigned short* __restrict__ w1bf, unsigned short* __restrict__ w2bf) {
    int i = blockIdx.x * 256 + threadIdx.x;
    if (i < 128 * 128) { int k = i >> 7, f = i & 127; w1bf[f * 128 + k] = f2bf(W1[i]); }
    if (i < 128 * 64)  { int k = i >> 6, f = i & 63;  w2bf[f * 128 + k] = f2bf(W2[i]); }
}

// ---------- GEMM1 (MFMA): h1[n][128] bf16 node-major = dinv[n] * (x @ W1) ----------
__global__ __launch_bounds__(256) void gemm1_k(const float* __restrict__ x,
                                               const unsigned short* __restrict__ w1bf,
                                               const float* __restrict__ dinv,
                                               unsigned* __restrict__ h1, int Nn) {
    __shared__ __align__(16) unsigned short sA[128][136];  // W1^T [feat][k]
    __shared__ __align__(16) unsigned short sB[64][136];   // x [node][k] bf16
    int tid = threadIdx.x;
    int n0g = blockIdx.x * 64;
    {
        const uint4* src = (const uint4*)w1bf;
#pragma unroll
        for (int l = 0; l < 8; ++l) {
            int idx = tid + l * 256;
            int f = idx >> 4, kq = idx & 15;
            *(uint4*)&sA[f][kq * 8] = src[idx];
        }
    }
    {
        int n = tid >> 2, kq = tid & 3;
        int gn = n0g + n; if (gn >= Nn) gn = Nn - 1;
        const float4* xr = (const float4*)(x + (size_t)gn * 128 + kq * 32);
        unsigned short* dst = &sB[n][kq * 32];
#pragma unroll
        for (int i = 0; i < 8; ++i) {
            float4 v = xr[i];
            dst[i * 4 + 0] = f2bf(v.x); dst[i * 4 + 1] = f2bf(v.y);
            dst[i * 4 + 2] = f2bf(v.z); dst[i * 4 + 3] = f2bf(v.w);
        }
    }
    __syncthreads();
    int wave = tid >> 6, lane = tid & 63;
    int quad = lane >> 4, l16 = lane & 15;
    f32x4 z = {0.f, 0.f, 0.f, 0.f};
    f32x4 acc[8];
#pragma unroll
    for (int t = 0; t < 8; ++t) acc[t] = z;
#pragma unroll
    for (int kk = 0; kk < 4; ++kk) {
        int kb = kk * 32 + quad * 8;
        short8 a = *(const short8*)&sB[wave * 16 + l16][kb];
#pragma unroll
        for (int ft = 0; ft < 8; ++ft) {
            short8 b = *(const short8*)&sA[ft * 16 + l16][kb];
            acc[ft] = __builtin_amdgcn_mfma_f32_16x16x32_bf16(a, b, acc[ft], 0, 0, 0);
        }
    }
    // per-row dinv for pre-scaled h' = dinv * h
    float dv[4];
#pragma unroll
    for (int r = 0; r < 4; ++r) {
        int gn = n0g + wave * 16 + quad * 4 + r;
        if (gn >= Nn) gn = Nn - 1;
        dv[r] = dinv[gn];
    }
    __syncthreads();  // reuse sA as transpose buffer
    unsigned short (*sC)[136] = sA;
#pragma unroll
    for (int ft = 0; ft < 8; ++ft)
#pragma unroll
        for (int r = 0; r < 4; ++r)
            sC[wave * 16 + quad * 4 + r][ft * 16 + l16] = f2bf(dv[r] * acc[ft][r]);
    __syncthreads();
#pragma unroll
    for (int l = 0; l < 4; ++l) {
        int idx = tid + l * 256;
        int row = idx >> 4, q = idx & 15;
        int gn = n0g + row;
        if (gn < Nn)
            *(uint4*)&h1[(size_t)gn * 64 + q * 4] = *(uint4*)&sC[row][q * 8];
    }
}

// ---------- GEMM2 (MFMA): h2[n][64] bf16 node-major = dinv[n] * (hr @ W2) ----------
__global__ __launch_bounds__(256) void gemm2_k(const unsigned* __restrict__ hr,
                                               const unsigned short* __restrict__ w2bf,
                                               const float* __restrict__ dinv,
                                               unsigned* __restrict__ h2, int Nn) {
    __shared__ __align__(16) unsigned short sA[64][136];
    __shared__ __align__(16) unsigned short sB[64][136];
    int tid = threadIdx.x;
    int n0g = blockIdx.x * 64;
    {
        const uint4* src = (const uint4*)w2bf;
#pragma unroll
        for (int l = 0; l < 4; ++l) {
            int idx = tid + l * 256;
            int f = idx >> 4, kq = idx & 15;
            *(uint4*)&sA[f][kq * 8] = src[idx];
        }
    }
    {
        const uint4* src = (const uint4*)hr;
#pragma unroll
        for (int l = 0; l < 4; ++l) {
            int idx = tid + l * 256;
            int row = idx >> 4, q = idx & 15;
            int gn = n0g + row; if (gn >= Nn) gn = Nn - 1;
            *(uint4*)&sB[row][q * 8] = src[(size_t)gn * 16 + q];
        }
    }
    __syncthreads();
    int wave = tid >> 6, lane = tid & 63;
    int quad = lane >> 4, l16 = lane & 15;
    f32x4 z = {0.f, 0.f, 0.f, 0.f};
    f32x4 acc[4];
#pragma unroll
    for (int t = 0; t < 4; ++t) acc[t] = z;
#pragma unroll
    for (int kk = 0; kk < 4; ++kk) {
        int kb = kk * 32 + quad * 8;
        short8 a = *(const short8*)&sB[wave * 16 + l16][kb];
#pragma unroll
        for (int ft = 0; ft < 4; ++ft) {
            short8 b = *(const short8*)&sA[ft * 16 + l16][kb];
            acc[ft] = __builtin_amdgcn_mfma_f32_16x16x32_bf16(a, b, acc[ft], 0, 0, 0);
        }
    }
    float dv[4];
#pragma unroll
    for (int r = 0; r < 4; ++r) {
        int gn = n0g + wave * 16 + quad * 4 + r;
        if (gn >= Nn) gn = Nn - 1;
        dv[r] = dinv[gn];
    }
    __syncthreads();
    unsigned short (*sC)[136] = sA;
#pragma unroll
    for (int ft = 0; ft < 4; ++ft)
#pragma unroll
        for (int r = 0; r < 4; ++r)
            sC[wave * 16 + quad * 4 + r][ft * 16 + l16] = f2bf(dv[r] * acc[ft][r]);
    __syncthreads();
#pragma unroll
    for (int l = 0; l < 2; ++l) {
        int idx = tid + l * 256;
        int row = idx >> 3, q = idx & 7;
        int gn = n0g + row;
        if (gn < Nn)
            *(uint4*)&h2[(size_t)gn * 32 + q * 4] = *(uint4*)&sC[row][q * 8];
    }
}

// ---------- agg1: wave=node, uint4 gathers (16 lanes/row, 4 edges/load) ----------
// h pre-scaled by dinv[src]; out[dst] = relu( di * (sum h'[src] + h'[self]) + b )
__global__ __launch_bounds__(256) void agg1_k(const unsigned* __restrict__ h,
                                              const int* __restrict__ row_ptr,
                                              const int* __restrict__ cnt,
                                              const int* __restrict__ colv,
                                              const float* __restrict__ dinv,
                                              const float* __restrict__ bias,
                                              unsigned* __restrict__ out, int Nn, int E) {
    int node = blockIdx.x * 4 + (threadIdx.x >> 6);
    if (node >= Nn) return;
    int lane = threadIdx.x & 63;
    int qtr = lane >> 4, fp = lane & 15;   // 16 lanes x 16B = one 256B row
    float di = dinv[node];
    int start = row_ptr[node];
    int deg = cnt[node];
    const uint4* hq = (const uint4*)h;     // row = 16 uint4

    f32x2 a0 = {0.f, 0.f}, a1 = a0, a2 = a0, a3 = a0;  // features 8fp..8fp+7
    if (qtr == 0) {
        uint4 u = hq[(size_t)node * 16 + fp];          // self (already * di)
        bfacc4(u, a0, a1, a2, a3);
    }

    for (int base = 0; base < deg; base += 64) {
        int idx = base + lane;
        int ci = start + idx; if (ci >= E) ci = E - 1;
        int sl = colv[ci];
        int m = deg - base; if (m > 64) m = 64;
        int j = 0;
        for (; j + 16 <= m; j += 16) {     // 4 loads x 4 edges
            int s0 = __shfl(sl, j + qtr);
            int s1 = __shfl(sl, j + 4 + qtr);
            int s2 = __shfl(sl, j + 8 + qtr);
            int s3 = __shfl(sl, j + 12 + qtr);
            uint4 u0 = hq[(size_t)s0 * 16 + fp];
            uint4 u1 = hq[(size_t)s1 * 16 + fp];
            uint4 u2 = hq[(size_t)s2 * 16 + fp];
            uint4 u3 = hq[(size_t)s3 * 16 + fp];
            bfacc4(u0, a0, a1, a2, a3);
            bfacc4(u1, a0, a1, a2, a3);
            bfacc4(u2, a0, a1, a2, a3);
            bfacc4(u3, a0, a1, a2, a3);
        }
        for (; j + 4 <= m; j += 4) {
            int s0 = __shfl(sl, j + qtr);
            uint4 u0 = hq[(size_t)s0 * 16 + fp];
            bfacc4(u0, a0, a1, a2, a3);
        }
        if (j < m) {                        // 1..3 edges left
            int q = j + qtr;
            int s = __shfl(sl, (q < m) ? q : j);
            if (q < m) {
                uint4 u = hq[(size_t)s * 16 + fp];
                bfacc4(u, a0, a1, a2, a3);
            }
        }
    }
    // combine the 4 quarter-copies of each feature
#define RED2(v) v += __shfl_xor(v, 32); v += __shfl_xor(v, 16)
    RED2(a0.x); RED2(a0.y); RED2(a1.x); RED2(a1.y);
    RED2(a2.x); RED2(a2.y); RED2(a3.x); RED2(a3.y);
#undef RED2
    if (qtr == 0) {
        float4 b0 = *(const float4*)&bias[8 * fp];
        float4 b1 = *(const float4*)&bias[8 * fp + 4];
        uint4 o;
        o.x = packbf(fmaxf(fmaf(di, a0.x, b0.x), 0.f), fmaxf(fmaf(di, a0.y, b0.y), 0.f));
        o.y = packbf(fmaxf(fmaf(di, a1.x, b0.z), 0.f), fmaxf(fmaf(di, a1.y, b0.w), 0.f));
        o.z = packbf(fmaxf(fmaf(di, a2.x, b1.x), 0.f), fmaxf(fmaf(di, a2.y, b1.y), 0.f));
        o.w = packbf(fmaxf(fmaf(di, a3.x, b1.z), 0.f), fmaxf(fmaf(di, a3.y, b1.w), 0.f));
        *(uint4*)&out[(size_t)node * 64 + 4 * fp] = o;   // regular store: gemm2 re-reads
    }
}

// ---------- agg2: wave=node, uint4 gathers (8 lanes/row, 8 edges/load) ----------
__global__ __launch_bounds__(256) void agg2_k(const unsigned* __restrict__ h,
                                              const int* __restrict__ row_ptr,
                                              const int* __restrict__ cnt,
                                              const int* __restrict__ colv,
                                              const float* __restrict__ dinv,
                                              const float* __restrict__ bias,
                                              float* __restrict__ out, int Nn, int E) {
    int node = blockIdx.x * 4 + (threadIdx.x >> 6);
    if (node >= Nn) return;
    int lane = threadIdx.x & 63;
    int oct = lane >> 3, fp = lane & 7;    // 8 lanes x 16B = one 128B row
    float di = dinv[node];
    int start = row_ptr[node];
    int deg = cnt[node];
    const uint4* hq = (const uint4*)h;     // row = 8 uint4

    f32x2 a0 = {0.f, 0.f}, a1 = a0, a2 = a0, a3 = a0;  // features 8fp..8fp+7
    if (oct == 0) {
        uint4 u = hq[(size_t)node * 8 + fp];           // self (already * di)
        bfacc4(u, a0, a1, a2, a3);
    }

    for (int base = 0; base < deg; base += 64) {
        int idx = base + lane;
        int ci = start + idx; if (ci >= E) ci = E - 1;
        int sl = __builtin_nontemporal_load(colv + ci);
        int m = deg - base; if (m > 64) m = 64;
        int j = 0;
        for (; j + 32 <= m; j += 32) {     // 4 loads x 8 edges
            int s0 = __shfl(sl, j + oct);
            int s1 = __shfl(sl, j + 8 + oct);
            int s2 = __shfl(sl, j + 16 + oct);
            int s3 = __shfl(sl, j + 24 + oct);
            uint4 u0 = hq[(size_t)s0 * 8 + fp];
            uint4 u1 = hq[(size_t)s1 * 8 + fp];
            uint4 u2 = hq[(size_t)s2 * 8 + fp];
            uint4 u3 = hq[(size_t)s3 * 8 + fp];
            bfacc4(u0, a0, a1, a2, a3);
            bfacc4(u1, a0, a1, a2, a3);
            bfacc4(u2, a0, a1, a2, a3);
            bfacc4(u3, a0, a1, a2, a3);
        }
        for (; j + 8 <= m; j += 8) {
            int s0 = __shfl(sl, j + oct);
            uint4 u0 = hq[(size_t)s0 * 8 + fp];
            bfacc4(u0, a0, a1, a2, a3);
        }
        if (j < m) {                        // 1..7 edges left
            int q = j + oct;
            int s = __shfl(sl, (q < m) ? q : j);
            if (q < m) {
                uint4 u = hq[(size_t)s * 8 + fp];
                bfacc4(u, a0, a1, a2, a3);
            }
        }
    }
    // combine the 8 octet-copies of each feature
#define RED3(v) v += __shfl_xor(v, 32); v += __shfl_xor(v, 16); v += __shfl_xor(v, 8)
    RED3(a0.x); RED3(a0.y); RED3(a1.x); RED3(a1.y);
    RED3(a2.x); RED3(a2.y); RED3(a3.x); RED3(a3.y);
#undef RED3
    if (oct == 0) {
        float4 b0 = *(const float4*)&bias[8 * fp];
        float4 b1 = *(const float4*)&bias[8 * fp + 4];
        float4 o0 = make_float4(fmaf(di, a0.x, b0.x), fmaf(di, a0.y, b0.y),
                                fmaf(di, a1.x, b0.z), fmaf(di, a1.y, b0.w));
        float4 o1 = make_float4(fmaf(di, a2.x, b1.x), fmaf(di, a2.y, b1.y),
                                fmaf(di, a3.x, b1.z), fmaf(di, a3.y, b1.w));
        *(float4*)&out[(size_t)node * 64 + 8 * fp]     = o0;
        *(float4*)&out[(size_t)node * 64 + 8 * fp + 4] = o1;
    }
}

// ---------- launch ----------
extern "C" void kernel_launch(void* const* d_in, const int* in_sizes, int n_in,
                              void* d_out, int out_size, void* d_ws, size_t ws_size,
                              hipStream_t stream) {
    const float* x  = (const float*)d_in[0];
    const void*  ei = d_in[1];
    const float* W1 = (const float*)d_in[2];
    const float* b1 = (const float*)d_in[3];
    const float* W2 = (const float*)d_in[4];
    const float* b2 = (const float*)d_in[5];

    const int N = N_NODES;
    const int E = in_sizes[1] / 2;
    const int NB = NBLK * NBUCK;  // 200192

    char* w = (char*)d_ws;
    size_t off = 0;
    auto take = [&](size_t bytes) {
        void* p = w + off;
        off = (off + bytes + 255) & ~(size_t)255;
        return p;
    };
    int*   flag    = (int*)take(2 * sizeof(int));
    int*   tot     = flag + 1;
    int*   cnt     = (int*)take((size_t)N * 4);
    int*   row_ptr = (int*)take((size_t)N * 4);
    int*   bsumA   = (int*)take(256 * 4);
    int*   bsumB   = (int*)take(256 * 4);
    int*   bhist   = (int*)take((size_t)NB * 4);
    int*   bbase   = (int*)take((size_t)NB * 4);
    float* dinv    = (float*)take((size_t)N * 4);
    unsigned* pairs = (unsigned*)take((size_t)E * 4);
    int*   colv    = (int*)take((size_t)E * 4);
    unsigned short* w1bf = (unsigned short*)take(128 * 128 * 2);
    unsigned short* w2bf = (unsigned short*)take(64 * 128 * 2);
    unsigned* hr   = (unsigned*)take((size_t)N * 64 * 4);   // bf16 [N][128]
    unsigned* h2   = (unsigned*)take((size_t)N * 32 * 4);   // bf16 [N][64]
    (void)ws_size; (void)n_in; (void)out_size;

    unsigned* h1 = (unsigned*)d_out;  // bf16 [N][128] in d_out, dead before agg2 writes

    const int nscanN = (N + 1023) / 1024;   // 98
    const int nscanB = (NB + 1023) / 1024;  // 196

    detect64_k<<<1, 64, 0, stream>>>((const unsigned long long*)ei, flag);
    count1_k<<<NBLK, 256, 0, stream>>>(ei, flag, bhist, E);
    // bucket-base scan (exclusive over bucket-major [NBUCK][NBLK])
    scan1_k<<<nscanB, 256, 0, stream>>>(bhist, bbase, bsumB, NB);
    scan2_k<<<1, 256, 0, stream>>>(bsumB, nscanB);
    scanadd_k<<<nscanB, 256, 0, stream>>>(bsumB, bbase, bhist, tot, NB);
    // stage pairs, then block-private degrees
    write1_k<<<NBLK, 256, 0, stream>>>(ei, flag, bbase, pairs, E);
    degree_k<<<NBUCK, 256, 0, stream>>>(pairs, bbase, tot, cnt, N);
    // degree scan -> row_ptr, dinv
    scan1_k<<<nscanN, 256, 0, stream>>>(cnt, row_ptr, bsumA, N);
    scan2_k<<<1, 256, 0, stream>>>(bsumA, nscanN);
    scan3_k<<<nscanN, 256, 0, stream>>>(bsumA, cnt, row_ptr, dinv, N);
    // block-private CSR scatter
    fill3_k<<<NBUCK, 256, 0, stream>>>(pairs, bbase, tot, row_ptr, colv, N);
    prep_w_k<<<64, 256, 0, stream>>>(W1, W2, w1bf, w2bf);

    gemm1_k<<<(N + 63) / 64, 256, 0, stream>>>(x, w1bf, dinv, h1, N);
    agg1_k<<<(N + 3) / 4, 256, 0, stream>>>(h1, row_ptr, cnt, colv, dinv, b1, hr, N, E);
    gemm2_k<<<(N + 63) / 64, 256, 0, stream>>>(hr, w2bf, dinv, h2, N);
    agg2_k<<<(N + 3) / 4, 256, 0, stream>>>(h2, row_ptr, cnt, colv, dinv, b2, (float*)d_out, N, E);
}